// Round 8
// baseline (461.992 us; speedup 1.0000x reference)
//
#include <hip/hip_runtime.h>
#include <hip/hip_bf16.h>
#include <stdint.h>

// Problem constants (fixed by setup_inputs)
#define M_TOT 8192
#define N_TOT 4096
#define K_TOT 4096
#define GROUP 128

// Round-2 lesson: fp16 reference arrays arrive as FLOAT32 ("else float*" rule).
// Round-4 lesson: fused one-pass is barrier/latency-bound; two-pass wins.
// Round-5 lesson: XOR chunk swizzle on global side of global_load_lds ->
//   0 LDS bank conflicts (measured).
// Round-6 lesson: 256^2 8-phase + counted vmcnt: gemm 249us/49% (GOLDEN).
// Rounds 7-10 (ALL REGRESSED): mod-3 buffers, no-lgkm0+TAIL vmcnt, deep
//   A-prefetch. Schedule hypothesis space exhausted; r1 waits/stages frozen.
// Round-11: r1 reproduces 245-247us/50% -> stable.
// Round-12: codegen port (2-tile unroll literal bufs, lgkm8 pre-drain,
//   hoisted global bases): 241.5us/50.5% (+1.5%). Addressing was not the
//   stall either. Schedule + codegen now both frozen.
// Round-13 (this round): MFMA shape 16x16x32 -> 32x32x16. u-bench: 32x32
//   pipe = 2495 TF vs 16x16 = 2176 (m119), ~15% faster per FLOP; AITER
//   hand-asm uses 32x32. Schedule/stage/wait structure UNTOUCHED (same
//   12-read ph0, 4-read ph1-3, same DMA, same swizzle -> 2-way max).
//   Wave tile 128x64 = 4mt x 2nt of 32x32, K-step 16 (ks 0..3).
//   A/B frag: row=l&31, k=(l>>5)*8+j (doubling pattern of the verified
//   16x16x32 row=l&15, k=(l>>4)*8+j). C/D: col=lane&31,
//   row=(reg&3)+8*(reg>>2)+4*(lane>>5) (m74/m101-verified).

using f32x4  = __attribute__((ext_vector_type(4))) float;
using f32x16 = __attribute__((ext_vector_type(16))) float;
using bf16x8 = __attribute__((ext_vector_type(8))) __bf16;

typedef __attribute__((address_space(3))) void as3_void;
typedef const __attribute__((address_space(1))) void as1_void;

// ---------------- pass 1: fused prep (dequant blocks first, then cast) -------
// blocks [0, 4096):        dequant qweight -> Wt [N][K] bf16 (LDS transpose)
// blocks [4096, 20480):    cast x f32 -> bf16
__global__ __launch_bounds__(256) void prep(
    const float* __restrict__ x,
    const int*   __restrict__ qweight,  // [K/8, N]
    const int*   __restrict__ qzeros,   // [G, N/8]
    const float* __restrict__ scales,   // [G, N]
    const int*   __restrict__ g_idx,    // [K]
    __bf16* __restrict__ xb,            // [M, K]
    __bf16* __restrict__ Wt)            // [N, K]
{
    const int tid = threadIdx.x;
    if (blockIdx.x < 4096) {
        __shared__ __align__(16) unsigned short T[64 * 72];  // [64n][72k]
        const int k0 = (blockIdx.x & 63) * 64;
        const int n0 = (blockIdx.x >> 6) * 64;
        const int g  = g_idx[k0];       // 64-k tile sits in one group (64 | 128)

        #pragma unroll
        for (int i = 0; i < 2; ++i) {
            const int idx = tid + i * 256;  // 0..511
            const int r   = idx >> 6;       // 0..7  (8 k's each)
            const int n   = idx & 63;
            const int qi  = qweight[(size_t)((k0 >> 3) + r) * N_TOT + n0 + n];
            const int zi  = qzeros[g * (N_TOT / 8) + ((n0 + n) >> 3)];
            const float s = scales[g * N_TOT + n0 + n];
            const float zs = (float)(((zi >> ((n & 7) * 4)) & 0xF) + 1) * s;
            bf16x8 v;
            #pragma unroll
            for (int j = 0; j < 8; ++j)
                v[j] = (__bf16)((float)((qi >> (4 * j)) & 0xF) * s - zs);  // (w-z-1)*s
            *(bf16x8*)&T[n * 72 + r * 8] = v;
        }
        __syncthreads();

        const int n = tid >> 2;             // 0..63
        const int c = (tid & 3) * 16;       // 0,16,32,48
        const bf16x8 a = *(const bf16x8*)&T[n * 72 + c];
        const bf16x8 b = *(const bf16x8*)&T[n * 72 + c + 8];
        __bf16* dst = Wt + (size_t)(n0 + n) * K_TOT + k0 + c;
        *(bf16x8*)dst = a;
        *(bf16x8*)(dst + 8) = b;
    } else {
        const size_t t = (size_t)(blockIdx.x - 4096) * 256 + tid;
        // nontemporal: x is read exactly once; don't pollute L3.
        const f32x4 f0 = __builtin_nontemporal_load((const f32x4*)(x + t * 8));
        const f32x4 f1 = __builtin_nontemporal_load((const f32x4*)(x + t * 8) + 1);
        bf16x8 v;
        v[0]=(__bf16)f0.x; v[1]=(__bf16)f0.y; v[2]=(__bf16)f0.z; v[3]=(__bf16)f0.w;
        v[4]=(__bf16)f1.x; v[5]=(__bf16)f1.y; v[6]=(__bf16)f1.z; v[7]=(__bf16)f1.w;
        *(bf16x8*)(xb + t * 8) = v;
    }
}

// ------- pass 2: 256^2 8-phase bf16 GEMM (B^T), XOR-swizzled LDS -------
// r1 GOLDEN schedule (barrier/wait/stage placement identical); r12 codegen
// (2-tile unroll, lgkm8, hoisted bases); r13 swaps MFMA shape to 32x32x16.
#define GBM 256
#define GBN 256
#define GBK 64
#define NKT (K_TOT / GBK)   // 64

#define BAR() do { asm volatile("" ::: "memory"); \
                   __builtin_amdgcn_s_barrier();  \
                   asm volatile("" ::: "memory"); } while (0)
#define WAIT_LGKM0() asm volatile("s_waitcnt lgkmcnt(0)" ::: "memory")
#define WAIT_LGKM8() asm volatile("s_waitcnt lgkmcnt(8)" ::: "memory")
#define WAIT_VM4()   asm volatile("s_waitcnt vmcnt(4)"   ::: "memory")
#define WAIT_VM0()   asm volatile("s_waitcnt vmcnt(0)"   ::: "memory")

// 8 MFMA (32x32x16) for M-band mt: all nt, all 4 K-steps.
#define MFMAPH(mt)                                                            \
    _Pragma("unroll")                                                         \
    for (int ks = 0; ks < 4; ++ks)                                            \
        _Pragma("unroll")                                                     \
        for (int nt = 0; nt < 2; ++nt)                                        \
            acc[(mt)][nt] = __builtin_amdgcn_mfma_f32_32x32x16_bf16(          \
                av[ks], bv[nt][ks], acc[(mt)][nt], 0, 0, 0);

// Phase q (q=1..3): read A-band q (4 ds_read_b128), issue stage, barrier,
// lgkmcnt(0), 8 MFMA under setprio(1), barrier.  (r1 pattern.)
#define PHASE_Q(BUF, q, STAGE_STMT)                                           \
    {                                                                         \
        bf16x8 av[4];                                                         \
        _Pragma("unroll")                                                     \
        for (int ks = 0; ks < 4; ++ks) av[ks] = ldA(BUF, q, ks);              \
        STAGE_STMT;                                                           \
        BAR();                                                                \
        WAIT_LGKM0();                                                         \
        __builtin_amdgcn_s_setprio(1);                                        \
        MFMAPH(q);                                                            \
        __builtin_amdgcn_s_setprio(0);                                        \
        BAR();                                                                \
    }

// One K-tile, literal buffer index BUF. Phase 0: 8 B-frags + A band 0
// (12 ds_read_b128) with lgkmcnt(8) pre-drain before the barrier.
#define KTILE(BUF, SA0, SA1, SB2, SB3, TAILW)                                 \
    {                                                                         \
        _Pragma("unroll")                                                     \
        for (int nt = 0; nt < 2; ++nt)                                        \
            _Pragma("unroll")                                                 \
            for (int ks = 0; ks < 4; ++ks)                                    \
                bv[nt][ks] = ldB(BUF, nt, ks);                                \
        {                                                                     \
            bf16x8 av[4];                                                     \
            _Pragma("unroll")                                                 \
            for (int ks = 0; ks < 4; ++ks) av[ks] = ldA(BUF, 0, ks);          \
            SA0;                                                              \
            WAIT_LGKM8();                                                     \
            BAR();                                                            \
            WAIT_LGKM0();                                                     \
            __builtin_amdgcn_s_setprio(1);                                    \
            MFMAPH(0);                                                        \
            __builtin_amdgcn_s_setprio(0);                                    \
            BAR();                                                            \
        }                                                                     \
        PHASE_Q(BUF, 1, SA1);                                                 \
        PHASE_Q(BUF, 2, SB2);                                                 \
        PHASE_Q(BUF, 3, SB3);                                                 \
        TAILW;                                                                \
    }

__global__ __launch_bounds__(512, 2) void gemm8p(
    const __bf16* __restrict__ xb,   // [M, K]
    const __bf16* __restrict__ Wt,   // [N, K]
    const float*  __restrict__ bias, // [N]
    float* __restrict__ out)         // [M, N]
{
    // [buf][mat: 0=A,1=B][256 rows * 64 k] ushort = 128 KiB total
    __shared__ __align__(16) unsigned short LDS[2][2][GBM * GBK];

    const int tid  = threadIdx.x;
    const int wid  = tid >> 6;
    const int lane = tid & 63;
    const int l31  = lane & 31;
    const int hi   = lane >> 5;

    // XCD-aware bijective swizzle (nwg = 512, divisible by 8)
    int bid = blockIdx.x;
    bid = (bid & 7) * (512 >> 3) + (bid >> 3);
    const int tn = bid & (N_TOT / GBN - 1);   // 0..15
    const int tm = bid >> 4;                  // 0..31
    const int m0 = tm * GBM;
    const int n0 = tn * GBN;

    const int wm = (wid >> 2) * 128;  // 0 or 128 (M-wave)
    const int wn = (wid & 3) * 64;    // 0..192   (N-wave)

    f32x16 acc[4][2];  // 4 M-bands x 2 N-tiles of 32x32
    #pragma unroll
    for (int i = 0; i < 4; ++i)
        #pragma unroll
        for (int j = 0; j < 2; ++j)
            acc[i][j] = (f32x16)0.f;

    // Hoisted per-thread global stage bases (r12). rl&7 == (tid>>3)&7 for
    // all j (j*64 = 0 mod 8) -> per-thread row/swizzle term loop-invariant.
    const int rl0 = tid >> 3;                       // 0..63
    const int kc0 = (tid & 7) ^ (rl0 & 7);          // XOR swizzle (global side)
    const __bf16* gA = xb + (size_t)(m0 + rl0) * K_TOT + kc0 * 8;
    const __bf16* gB = Wt + (size_t)(n0 + rl0) * K_TOT + kc0 * 8;

    // Stage one half-tile (128 rows x 64 k) into LDS[bf][mat], half h.
    // 2 x global_load_lds (16B)/thread; gbase is the hoisted per-thread base.
    auto stage = [&](int bf, int mat, int h, const __bf16* gbase, int kt) {
        #pragma unroll
        for (int j = 0; j < 2; ++j) {
            const __bf16* ga = gbase
                + (size_t)(h * 128 + j * 64) * K_TOT + kt * GBK;
            __builtin_amdgcn_global_load_lds((as1_void*)ga,
                (as3_void*)&LDS[bf][mat][h * 8192 + (j * 512 + wid * 64) * 8],
                16, 0, 0);
        }
    };
    // 32x32x16 operand frags: row = l&31, k = ks*16 + (l>>5)*8 + j
    // -> 8-elem chunk index c = ks*2 + hi, XOR'd with row&7 (same swizzle).
    auto ldA = [&](int bf, int mt, int ks) -> bf16x8 {
        const int r = wm + mt * 32 + l31;
        const int c = ks * 2 + hi;
        return *(const bf16x8*)
            &LDS[bf][0][r * GBK + ((c ^ (r & 7)) << 3)];
    };
    auto ldB = [&](int bf, int nt, int ks) -> bf16x8 {
        const int r = wn + nt * 32 + l31;
        const int c = ks * 2 + hi;
        return *(const bf16x8*)
            &LDS[bf][1][r * GBK + ((c ^ (r & 7)) << 3)];
    };

    // Prologue: A(0),B(0) -> buf0; B(1) -> buf1. vmcnt(4) = A(0),B(0) landed,
    // B(1) (4 loads) still in flight.
    stage(0, 0, 0, gA, 0); stage(0, 0, 1, gA, 0);
    stage(0, 1, 0, gB, 0); stage(0, 1, 1, gB, 0);
    stage(1, 1, 0, gB, 1); stage(1, 1, 1, gB, 1);
    WAIT_VM4();
    BAR();

    bf16x8 bv[2][4];  // B frags held in regs across the whole K-tile

    // 2 K-tiles per iteration -> literal buf indices. Stage slots and waits
    // r1-verbatim per tile: ph0/ph1: A(t+1) -> other buf; ph2/ph3: B(t+2) ->
    // same buf; end-of-tile vmcnt(4), vmcnt(0) at the tail.
    for (int tt = 0; tt < NKT / 2; ++tt) {
        const int t0 = 2 * tt, t1 = 2 * tt + 1;
        const bool last = (tt == NKT / 2 - 1);

        KTILE(0,
              stage(1, 0, 0, gA, t0 + 1),
              stage(1, 0, 1, gA, t0 + 1),
              if (!last) stage(0, 1, 0, gB, t0 + 2),
              if (!last) stage(0, 1, 1, gB, t0 + 2),
              if (!last) { WAIT_VM4(); } else { WAIT_VM0(); });

        KTILE(1,
              if (!last) stage(0, 0, 0, gA, t1 + 1),
              if (!last) stage(0, 0, 1, gA, t1 + 1),
              if (!last) stage(1, 1, 0, gB, t1 + 2),
              if (!last) stage(1, 1, 1, gB, t1 + 2),
              if (!last) { WAIT_VM4(); } else { WAIT_VM0(); });
    }

    // epilogue: 32x32 C/D layout col=lane&31,
    // row = (reg&3) + 8*(reg>>2) + 4*(lane>>5)  (m74/m101-verified)
    #pragma unroll
    for (int nt = 0; nt < 2; ++nt) {
        const int col = n0 + wn + nt * 32 + l31;
        const float bb = bias[col];
        #pragma unroll
        for (int mt = 0; mt < 4; ++mt) {
            const int rowb = m0 + wm + mt * 32 + 4 * hi;
            #pragma unroll
            for (int reg = 0; reg < 16; ++reg) {
                const int row = rowb + (reg & 3) + 8 * (reg >> 2);
                out[(size_t)row * N_TOT + col] = acc[mt][nt][reg] + bb;
            }
        }
    }
}

// ---------------- fallback: round-4 fused kernel (proven correct) ----------------
#define FBM 256
#define FBN 128
#define FBKP 72

__global__ __launch_bounds__(256, 2) void gptq_gemm_fused(
    const float* __restrict__ x, const int* __restrict__ qweight,
    const int* __restrict__ qzeros, const float* __restrict__ scales,
    const int* __restrict__ g_idx, const float* __restrict__ bias,
    float* __restrict__ out)
{
    __shared__ __align__(16) unsigned short As[FBM * FBKP];
    __shared__ __align__(16) unsigned short Bt[FBN * FBKP];

    const int tid  = threadIdx.x;
    const int wave = tid >> 6;
    const int lane = tid & 63;
    const int n0 = blockIdx.x * FBN;
    const int m0 = blockIdx.y * FBM;
    const int wm = (wave >> 1) * 64;
    const int wn = (wave & 1) * 64;
    const int l15  = lane & 15;
    const int quad = lane >> 4;

    f32x4 acc[2][4][4];
    #pragma unroll
    for (int mi = 0; mi < 2; ++mi)
        #pragma unroll
        for (int i = 0; i < 4; ++i)
            #pragma unroll
            for (int j = 0; j < 4; ++j)
                acc[mi][i][j] = (f32x4)0.f;

    const int nb  = tid & 31;
    const int r   = tid >> 5;
    const int zsh = (nb & 7) * 4;

    for (int kt = 0; kt < K_TOT / 64; ++kt) {
        const int k0 = kt * 64;
        #pragma unroll
        for (int i = 0; i < 8; ++i) {
            const int c   = tid + i * 256;
            const int row = c >> 3;
            const int cb  = (c & 7) << 3;
            const float* xp = x + (size_t)(m0 + row) * K_TOT + (k0 + cb);
            const float4 f0 = *(const float4*)xp;
            const float4 f1 = *(const float4*)(xp + 4);
            bf16x8 v;
            v[0]=(__bf16)f0.x; v[1]=(__bf16)f0.y; v[2]=(__bf16)f0.z; v[3]=(__bf16)f0.w;
            v[4]=(__bf16)f1.x; v[5]=(__bf16)f1.y; v[6]=(__bf16)f1.z; v[7]=(__bf16)f1.w;
            *(bf16x8*)&As[row * FBKP + cb] = v;
        }
        const int g    = g_idx[k0];
        const int qrow = (k0 >> 3) + r;
        #pragma unroll
        for (int dn = 0; dn < 4; ++dn) {
            const int n  = nb + dn * 32;
            const int qi = qweight[(size_t)qrow * N_TOT + (n0 + n)];
            const int zi = qzeros[g * (N_TOT / 8) + ((n0 + n) >> 3)];
            const float s = scales[g * N_TOT + (n0 + n)];
            const float zs = (float)(((zi >> zsh) & 0xF) + 1) * s;
            bf16x8 v;
            #pragma unroll
            for (int j = 0; j < 8; ++j)
                v[j] = (__bf16)((float)((qi >> (4 * j)) & 0xF) * s - zs);
            *(bf16x8*)&Bt[n * FBKP + r * 8] = v;
        }
        __syncthreads();
        #pragma unroll
        for (int ks = 0; ks < 2; ++ks) {
            bf16x8 bvv[4];
            #pragma unroll
            for (int nt = 0; nt < 4; ++nt)
                bvv[nt] = *(const bf16x8*)&Bt[(wn + nt * 16 + l15) * FBKP + ks * 32 + quad * 8];
            #pragma unroll
            for (int mi = 0; mi < 2; ++mi) {
                bf16x8 av[4];
                #pragma unroll
                for (int mt = 0; mt < 4; ++mt)
                    av[mt] = *(const bf16x8*)&As[(mi * 128 + wm + mt * 16 + l15) * FBKP + ks * 32 + quad * 8];
                #pragma unroll
                for (int mt = 0; mt < 4; ++mt)
                    #pragma unroll
                    for (int nt = 0; nt < 4; ++nt)
                        acc[mi][mt][nt] = __builtin_amdgcn_mfma_f32_16x16x32_bf16(
                            av[mt], bvv[nt], acc[mi][mt][nt], 0, 0, 0);
            }
        }
        __syncthreads();
    }
    #pragma unroll
    for (int mi = 0; mi < 2; ++mi)
        #pragma unroll
        for (int nt = 0; nt < 4; ++nt) {
            const int col = n0 + wn + nt * 16 + l15;
            const float bvv = bias[col];
            #pragma unroll
            for (int mt = 0; mt < 4; ++mt) {
                const int rowb = m0 + mi * 128 + wm + mt * 16 + quad * 4;
                #pragma unroll
                for (int i = 0; i < 4; ++i)
                    out[(size_t)(rowb + i) * N_TOT + col] = acc[mi][mt][nt][i] + bvv;
            }
        }
}

extern "C" void kernel_launch(void* const* d_in, const int* in_sizes, int n_in,
                              void* d_out, int out_size, void* d_ws, size_t ws_size,
                              hipStream_t stream) {
    const float* x  = (const float*)d_in[0];
    const int*   qw = (const int*)d_in[1];
    const int*   qz = (const int*)d_in[2];
    const float* sc = (const float*)d_in[3];
    const int*   gi = (const int*)d_in[4];
    const float* bs = (const float*)d_in[5];
    float* out = (float*)d_out;

    const size_t xb_bytes = (size_t)M_TOT * K_TOT * 2;   // 67,108,864
    const size_t wt_bytes = (size_t)N_TOT * K_TOT * 2;   // 33,554,432

    if (ws_size >= xb_bytes + wt_bytes) {
        __bf16* xb = (__bf16*)d_ws;
        __bf16* Wt = (__bf16*)((char*)d_ws + xb_bytes);
        const int cast_blocks = (M_TOT * K_TOT) / (256 * 8);   // 16384
        prep<<<dim3(4096 + cast_blocks), dim3(256), 0, stream>>>(
            x, qw, qz, sc, gi, xb, Wt);
        gemm8p<<<dim3((M_TOT / GBM) * (N_TOT / GBN)), dim3(512), 0, stream>>>(
            xb, Wt, bs, out);
    } else {
        gptq_gemm_fused<<<dim3(N_TOT / FBN, M_TOT / FBM), dim3(256), 0, stream>>>(
            x, qw, qz, sc, gi, bs, out);
    }
}

// Round 9
// 437.770 us; speedup vs baseline: 1.0553x; 1.0553x over previous
//
#include <hip/hip_runtime.h>
#include <hip/hip_bf16.h>
#include <stdint.h>

// Problem constants (fixed by setup_inputs)
#define M_TOT 8192
#define N_TOT 4096
#define K_TOT 4096
#define GROUP 128

// Round-2 lesson: fp16 reference arrays arrive as FLOAT32 ("else float*" rule).
// Round-4 lesson: fused one-pass is barrier/latency-bound; two-pass wins.
// Round-5 lesson: XOR chunk swizzle on global side of global_load_lds ->
//   0 LDS bank conflicts (measured).
// Round-6 lesson: 256^2 8-phase + counted vmcnt: gemm 249us/49% (GOLDEN).
// Rounds 7-10 (ALL REGRESSED): mod-3 buffers, no-lgkm0+TAIL vmcnt, deep
//   A-prefetch. Schedule hypothesis space exhausted; r1 waits/stages frozen.
// Round-11: r1 reproduces 245-247us/50% -> stable.
// Round-12: codegen port (2-tile unroll literal bufs, lgkm8 pre-drain,
//   hoisted global bases): 241.5us/50.5% (+1.5%). BEST CONFIG -- this file.
// Round-13 lesson (REGRESSED, reverted): MFMA 32x32x16 swap -> correct
//   numerics but SQ_LDS_BANK_CONFLICT 0 -> 2.5e7 (267.5us/46%). With 32x32
//   frags, 32 lanes share one chunk column and only r&7 spreads banks ->
//   4-way conflicts; unfixable under lane-linear global_load_lds dst (8
//   chunk slots/row). 32x32 is structurally incompatible with DMA-staged
//   [256][64] tiles; 16x16x32 + quad-indexed chunks is the conflict-free
//   pairing. FINAL: r12 configuration.

using f32x4  = __attribute__((ext_vector_type(4))) float;
using bf16x8 = __attribute__((ext_vector_type(8))) __bf16;

typedef __attribute__((address_space(3))) void as3_void;
typedef const __attribute__((address_space(1))) void as1_void;

// ---------------- pass 1: fused prep (dequant blocks first, then cast) -------
// blocks [0, 4096):        dequant qweight -> Wt [N][K] bf16 (LDS transpose)
// blocks [4096, 20480):    cast x f32 -> bf16
__global__ __launch_bounds__(256) void prep(
    const float* __restrict__ x,
    const int*   __restrict__ qweight,  // [K/8, N]
    const int*   __restrict__ qzeros,   // [G, N/8]
    const float* __restrict__ scales,   // [G, N]
    const int*   __restrict__ g_idx,    // [K]
    __bf16* __restrict__ xb,            // [M, K]
    __bf16* __restrict__ Wt)            // [N, K]
{
    const int tid = threadIdx.x;
    if (blockIdx.x < 4096) {
        __shared__ __align__(16) unsigned short T[64 * 72];  // [64n][72k]
        const int k0 = (blockIdx.x & 63) * 64;
        const int n0 = (blockIdx.x >> 6) * 64;
        const int g  = g_idx[k0];       // 64-k tile sits in one group (64 | 128)

        #pragma unroll
        for (int i = 0; i < 2; ++i) {
            const int idx = tid + i * 256;  // 0..511
            const int r   = idx >> 6;       // 0..7  (8 k's each)
            const int n   = idx & 63;
            const int qi  = qweight[(size_t)((k0 >> 3) + r) * N_TOT + n0 + n];
            const int zi  = qzeros[g * (N_TOT / 8) + ((n0 + n) >> 3)];
            const float s = scales[g * N_TOT + n0 + n];
            const float zs = (float)(((zi >> ((n & 7) * 4)) & 0xF) + 1) * s;
            bf16x8 v;
            #pragma unroll
            for (int j = 0; j < 8; ++j)
                v[j] = (__bf16)((float)((qi >> (4 * j)) & 0xF) * s - zs);  // (w-z-1)*s
            *(bf16x8*)&T[n * 72 + r * 8] = v;
        }
        __syncthreads();

        const int n = tid >> 2;             // 0..63
        const int c = (tid & 3) * 16;       // 0,16,32,48
        const bf16x8 a = *(const bf16x8*)&T[n * 72 + c];
        const bf16x8 b = *(const bf16x8*)&T[n * 72 + c + 8];
        __bf16* dst = Wt + (size_t)(n0 + n) * K_TOT + k0 + c;
        *(bf16x8*)dst = a;
        *(bf16x8*)(dst + 8) = b;
    } else {
        const size_t t = (size_t)(blockIdx.x - 4096) * 256 + tid;
        // nontemporal: x is read exactly once; don't pollute L3.
        const f32x4 f0 = __builtin_nontemporal_load((const f32x4*)(x + t * 8));
        const f32x4 f1 = __builtin_nontemporal_load((const f32x4*)(x + t * 8) + 1);
        bf16x8 v;
        v[0]=(__bf16)f0.x; v[1]=(__bf16)f0.y; v[2]=(__bf16)f0.z; v[3]=(__bf16)f0.w;
        v[4]=(__bf16)f1.x; v[5]=(__bf16)f1.y; v[6]=(__bf16)f1.z; v[7]=(__bf16)f1.w;
        *(bf16x8*)(xb + t * 8) = v;
    }
}

// ------- pass 2: 256^2 8-phase bf16 GEMM (B^T), XOR-swizzled LDS -------
// r1 GOLDEN schedule (barrier/wait/stage placement frozen); r12 codegen
// (2-tile unroll, lgkm8 pre-drain, hoisted bases); MFMA 16x16x32 (the
// conflict-free pairing with quad-indexed chunk columns -- see r13 lesson).
#define GBM 256
#define GBN 256
#define GBK 64
#define NKT (K_TOT / GBK)   // 64

#define BAR() do { asm volatile("" ::: "memory"); \
                   __builtin_amdgcn_s_barrier();  \
                   asm volatile("" ::: "memory"); } while (0)
#define WAIT_LGKM0() asm volatile("s_waitcnt lgkmcnt(0)" ::: "memory")
#define WAIT_LGKM8() asm volatile("s_waitcnt lgkmcnt(8)" ::: "memory")
#define WAIT_VM4()   asm volatile("s_waitcnt vmcnt(4)"   ::: "memory")
#define WAIT_VM0()   asm volatile("s_waitcnt vmcnt(0)"   ::: "memory")

// 16 MFMA into acc[base..base+1][0..3] from av (in scope) x bv.
#define MFMA8(base)                                                           \
    _Pragma("unroll")                                                         \
    for (int ks = 0; ks < 2; ++ks)                                            \
        _Pragma("unroll")                                                     \
        for (int mtl = 0; mtl < 2; ++mtl)                                     \
            _Pragma("unroll")                                                 \
            for (int nt = 0; nt < 4; ++nt)                                    \
                acc[(base) + mtl][nt] =                                       \
                    __builtin_amdgcn_mfma_f32_16x16x32_bf16(                  \
                        av[mtl][ks], bv[nt][ks], acc[(base) + mtl][nt],       \
                        0, 0, 0);

// Phase q (q=1..3): read A-quadrant (literal BUF), issue stage, barrier,
// lgkmcnt(0), 16 MFMA under setprio(1), barrier.  (r1 pattern.)
#define PHASE_Q(BUF, q, STAGE_STMT)                                           \
    {                                                                         \
        bf16x8 av[2][2];                                                      \
        _Pragma("unroll")                                                     \
        for (int ks = 0; ks < 2; ++ks) {                                      \
            av[0][ks] = ldA(BUF, 2 * (q), ks);                                \
            av[1][ks] = ldA(BUF, 2 * (q) + 1, ks);                            \
        }                                                                     \
        STAGE_STMT;                                                           \
        BAR();                                                                \
        WAIT_LGKM0();                                                         \
        __builtin_amdgcn_s_setprio(1);                                        \
        MFMA8(2 * (q));                                                       \
        __builtin_amdgcn_s_setprio(0);                                        \
        BAR();                                                                \
    }

// One K-tile, literal buffer index BUF. Phase 0: 8 B-frags + A quadrant 0
// (12 ds_read_b128) with lgkmcnt(8) pre-drain before the barrier (m201).
#define KTILE(BUF, SA0, SA1, SB2, SB3, TAILW)                                 \
    {                                                                         \
        _Pragma("unroll")                                                     \
        for (int nt = 0; nt < 4; ++nt)                                        \
            _Pragma("unroll")                                                 \
            for (int ks = 0; ks < 2; ++ks)                                    \
                bv[nt][ks] = ldB(BUF, nt, ks);                                \
        {                                                                     \
            bf16x8 av[2][2];                                                  \
            _Pragma("unroll")                                                 \
            for (int ks = 0; ks < 2; ++ks) {                                  \
                av[0][ks] = ldA(BUF, 0, ks);                                  \
                av[1][ks] = ldA(BUF, 1, ks);                                  \
            }                                                                 \
            SA0;                                                              \
            WAIT_LGKM8();                                                     \
            BAR();                                                            \
            WAIT_LGKM0();                                                     \
            __builtin_amdgcn_s_setprio(1);                                    \
            MFMA8(0);                                                         \
            __builtin_amdgcn_s_setprio(0);                                    \
            BAR();                                                            \
        }                                                                     \
        PHASE_Q(BUF, 1, SA1);                                                 \
        PHASE_Q(BUF, 2, SB2);                                                 \
        PHASE_Q(BUF, 3, SB3);                                                 \
        TAILW;                                                                \
    }

__global__ __launch_bounds__(512, 2) void gemm8p(
    const __bf16* __restrict__ xb,   // [M, K]
    const __bf16* __restrict__ Wt,   // [N, K]
    const float*  __restrict__ bias, // [N]
    float* __restrict__ out)         // [M, N]
{
    // [buf][mat: 0=A,1=B][256 rows * 64 k] ushort = 128 KiB total
    __shared__ __align__(16) unsigned short LDS[2][2][GBM * GBK];

    const int tid  = threadIdx.x;
    const int wid  = tid >> 6;
    const int lane = tid & 63;
    const int l15  = lane & 15;
    const int quad = lane >> 4;

    // XCD-aware bijective swizzle (nwg = 512, divisible by 8)
    int bid = blockIdx.x;
    bid = (bid & 7) * (512 >> 3) + (bid >> 3);
    const int tn = bid & (N_TOT / GBN - 1);   // 0..15
    const int tm = bid >> 4;                  // 0..31
    const int m0 = tm * GBM;
    const int n0 = tn * GBN;

    const int wm = (wid >> 2) * 128;  // 0 or 128 (M-wave)
    const int wn = (wid & 3) * 64;    // 0..192   (N-wave)

    f32x4 acc[8][4];
    #pragma unroll
    for (int i = 0; i < 8; ++i)
        #pragma unroll
        for (int j = 0; j < 4; ++j)
            acc[i][j] = (f32x4)0.f;

    // Hoisted per-thread global stage bases (r12). rl&7 == (tid>>3)&7 for
    // all j (j*64 = 0 mod 8) -> per-thread row/swizzle term loop-invariant.
    const int rl0 = tid >> 3;                       // 0..63
    const int kc0 = (tid & 7) ^ (rl0 & 7);          // XOR swizzle (global side)
    const __bf16* gA = xb + (size_t)(m0 + rl0) * K_TOT + kc0 * 8;
    const __bf16* gB = Wt + (size_t)(n0 + rl0) * K_TOT + kc0 * 8;

    // Stage one half-tile (128 rows x 64 k) into LDS[bf][mat], half h.
    // 2 x global_load_lds (16B)/thread; gbase is the hoisted per-thread base.
    auto stage = [&](int bf, int mat, int h, const __bf16* gbase, int kt) {
        #pragma unroll
        for (int j = 0; j < 2; ++j) {
            const __bf16* ga = gbase
                + (size_t)(h * 128 + j * 64) * K_TOT + kt * GBK;
            __builtin_amdgcn_global_load_lds((as1_void*)ga,
                (as3_void*)&LDS[bf][mat][h * 8192 + (j * 512 + wid * 64) * 8],
                16, 0, 0);
        }
    };
    auto ldA = [&](int bf, int mt, int ks) -> bf16x8 {
        const int r = wm + mt * 16 + l15;
        return *(const bf16x8*)
            &LDS[bf][0][r * GBK + (((ks * 4 + quad) ^ (r & 7)) << 3)];
    };
    auto ldB = [&](int bf, int nt, int ks) -> bf16x8 {
        const int r = wn + nt * 16 + l15;
        return *(const bf16x8*)
            &LDS[bf][1][r * GBK + (((ks * 4 + quad) ^ (r & 7)) << 3)];
    };

    // Prologue: A(0),B(0) -> buf0; B(1) -> buf1. vmcnt(4) = A(0),B(0) landed,
    // B(1) (4 loads) still in flight.
    stage(0, 0, 0, gA, 0); stage(0, 0, 1, gA, 0);
    stage(0, 1, 0, gB, 0); stage(0, 1, 1, gB, 0);
    stage(1, 1, 0, gB, 1); stage(1, 1, 1, gB, 1);
    WAIT_VM4();
    BAR();

    bf16x8 bv[4][2];  // B frags held in regs across the whole K-tile

    // 2 K-tiles per iteration -> literal buf indices. Stage slots and waits
    // r1-verbatim per tile: ph0/ph1: A(t+1) -> other buf; ph2/ph3: B(t+2) ->
    // same buf; end-of-tile vmcnt(4), vmcnt(0) at the tail.
    for (int tt = 0; tt < NKT / 2; ++tt) {
        const int t0 = 2 * tt, t1 = 2 * tt + 1;
        const bool last = (tt == NKT / 2 - 1);

        KTILE(0,
              stage(1, 0, 0, gA, t0 + 1),
              stage(1, 0, 1, gA, t0 + 1),
              if (!last) stage(0, 1, 0, gB, t0 + 2),
              if (!last) stage(0, 1, 1, gB, t0 + 2),
              if (!last) { WAIT_VM4(); } else { WAIT_VM0(); });

        KTILE(1,
              if (!last) stage(0, 0, 0, gA, t1 + 1),
              if (!last) stage(0, 0, 1, gA, t1 + 1),
              if (!last) stage(1, 1, 0, gB, t1 + 2),
              if (!last) stage(1, 1, 1, gB, t1 + 2),
              if (!last) { WAIT_VM4(); } else { WAIT_VM0(); });
    }

    // epilogue: C/D layout col=lane&15, row=quad*4+reg (m89/m91-verified)
    #pragma unroll
    for (int nt = 0; nt < 4; ++nt) {
        const int col = n0 + wn + nt * 16 + l15;
        const float bb = bias[col];
        #pragma unroll
        for (int mt = 0; mt < 8; ++mt) {
            const int rowb = m0 + wm + mt * 16 + quad * 4;
            #pragma unroll
            for (int i = 0; i < 4; ++i)
                out[(size_t)(rowb + i) * N_TOT + col] = acc[mt][nt][i] + bb;
        }
    }
}

// ---------------- fallback: round-4 fused kernel (proven correct) ----------------
#define FBM 256
#define FBN 128
#define FBKP 72

__global__ __launch_bounds__(256, 2) void gptq_gemm_fused(
    const float* __restrict__ x, const int* __restrict__ qweight,
    const int* __restrict__ qzeros, const float* __restrict__ scales,
    const int* __restrict__ g_idx, const float* __restrict__ bias,
    float* __restrict__ out)
{
    __shared__ __align__(16) unsigned short As[FBM * FBKP];
    __shared__ __align__(16) unsigned short Bt[FBN * FBKP];

    const int tid  = threadIdx.x;
    const int wave = tid >> 6;
    const int lane = tid & 63;
    const int n0 = blockIdx.x * FBN;
    const int m0 = blockIdx.y * FBM;
    const int wm = (wave >> 1) * 64;
    const int wn = (wave & 1) * 64;
    const int l15  = lane & 15;
    const int quad = lane >> 4;

    f32x4 acc[2][4][4];
    #pragma unroll
    for (int mi = 0; mi < 2; ++mi)
        #pragma unroll
        for (int i = 0; i < 4; ++i)
            #pragma unroll
            for (int j = 0; j < 4; ++j)
                acc[mi][i][j] = (f32x4)0.f;

    const int nb  = tid & 31;
    const int r   = tid >> 5;
    const int zsh = (nb & 7) * 4;

    for (int kt = 0; kt < K_TOT / 64; ++kt) {
        const int k0 = kt * 64;
        #pragma unroll
        for (int i = 0; i < 8; ++i) {
            const int c   = tid + i * 256;
            const int row = c >> 3;
            const int cb  = (c & 7) << 3;
            const float* xp = x + (size_t)(m0 + row) * K_TOT + (k0 + cb);
            const float4 f0 = *(const float4*)xp;
            const float4 f1 = *(const float4*)(xp + 4);
            bf16x8 v;
            v[0]=(__bf16)f0.x; v[1]=(__bf16)f0.y; v[2]=(__bf16)f0.z; v[3]=(__bf16)f0.w;
            v[4]=(__bf16)f1.x; v[5]=(__bf16)f1.y; v[6]=(__bf16)f1.z; v[7]=(__bf16)f1.w;
            *(bf16x8*)&As[row * FBKP + cb] = v;
        }
        const int g    = g_idx[k0];
        const int qrow = (k0 >> 3) + r;
        #pragma unroll
        for (int dn = 0; dn < 4; ++dn) {
            const int n  = nb + dn * 32;
            const int qi = qweight[(size_t)qrow * N_TOT + (n0 + n)];
            const int zi = qzeros[g * (N_TOT / 8) + ((n0 + n) >> 3)];
            const float s = scales[g * N_TOT + (n0 + n)];
            const float zs = (float)(((zi >> zsh) & 0xF) + 1) * s;
            bf16x8 v;
            #pragma unroll
            for (int j = 0; j < 8; ++j)
                v[j] = (__bf16)((float)((qi >> (4 * j)) & 0xF) * s - zs);
            *(bf16x8*)&Bt[n * FBKP + r * 8] = v;
        }
        __syncthreads();
        #pragma unroll
        for (int ks = 0; ks < 2; ++ks) {
            bf16x8 bvv[4];
            #pragma unroll
            for (int nt = 0; nt < 4; ++nt)
                bvv[nt] = *(const bf16x8*)&Bt[(wn + nt * 16 + l15) * FBKP + ks * 32 + quad * 8];
            #pragma unroll
            for (int mi = 0; mi < 2; ++mi) {
                bf16x8 av[4];
                #pragma unroll
                for (int mt = 0; mt < 4; ++mt)
                    av[mt] = *(const bf16x8*)&As[(mi * 128 + wm + mt * 16 + l15) * FBKP + ks * 32 + quad * 8];
                #pragma unroll
                for (int mt = 0; mt < 4; ++mt)
                    #pragma unroll
                    for (int nt = 0; nt < 4; ++nt)
                        acc[mi][mt][nt] = __builtin_amdgcn_mfma_f32_16x16x32_bf16(
                            av[mt], bvv[nt], acc[mi][mt][nt], 0, 0, 0);
            }
        }
        __syncthreads();
    }
    #pragma unroll
    for (int mi = 0; mi < 2; ++mi)
        #pragma unroll
        for (int nt = 0; nt < 4; ++nt) {
            const int col = n0 + wn + nt * 16 + l15;
            const float bvv = bias[col];
            #pragma unroll
            for (int mt = 0; mt < 4; ++mt) {
                const int rowb = m0 + mi * 128 + wm + mt * 16 + quad * 4;
                #pragma unroll
                for (int i = 0; i < 4; ++i)
                    out[(size_t)(rowb + i) * N_TOT + col] = acc[mi][mt][nt][i] + bvv;
            }
        }
}

extern "C" void kernel_launch(void* const* d_in, const int* in_sizes, int n_in,
                              void* d_out, int out_size, void* d_ws, size_t ws_size,
                              hipStream_t stream) {
    const float* x  = (const float*)d_in[0];
    const int*   qw = (const int*)d_in[1];
    const int*   qz = (const int*)d_in[2];
    const float* sc = (const float*)d_in[3];
    const int*   gi = (const int*)d_in[4];
    const float* bs = (const float*)d_in[5];
    float* out = (float*)d_out;

    const size_t xb_bytes = (size_t)M_TOT * K_TOT * 2;   // 67,108,864
    const size_t wt_bytes = (size_t)N_TOT * K_TOT * 2;   // 33,554,432

    if (ws_size >= xb_bytes + wt_bytes) {
        __bf16* xb = (__bf16*)d_ws;
        __bf16* Wt = (__bf16*)((char*)d_ws + xb_bytes);
        const int cast_blocks = (M_TOT * K_TOT) / (256 * 8);   // 16384
        prep<<<dim3(4096 + cast_blocks), dim3(256), 0, stream>>>(
            x, qw, qz, sc, gi, xb, Wt);
        gemm8p<<<dim3((M_TOT / GBM) * (N_TOT / GBN)), dim3(512), 0, stream>>>(
            xb, Wt, bs, out);
    } else {
        gptq_gemm_fused<<<dim3(N_TOT / FBN, M_TOT / FBM), dim3(256), 0, stream>>>(
            x, qw, qz, sc, gi, bs, out);
    }
}